// Round 6
// baseline (266.987 us; speedup 1.0000x reference)
//
#include <hip/hip_runtime.h>
#include <hip/hip_bf16.h>

#define DIM 128
#define BNODES 128      // dst nodes per bucket (dst>>7 = bucket, dst&127 = local)
#define NBMAX 1024      // bucket capacity in LDS hist (nb = 782 for N=100000)
#define BCAP 4096       // max edges per bucket region (mean 2046, +45 sigma)

typedef __attribute__((ext_vector_type(8))) short bf16x8;
typedef __attribute__((ext_vector_type(4))) float f32x4;

__device__ inline ushort f2bf(float f) {
    uint u = __float_as_uint(f);
    u += 0x7fffu + ((u >> 16) & 1u);   // RNE
    return (ushort)(u >> 16);
}
__device__ inline uint pack2(float lo, float hi) {
    return (uint)f2bf(lo) | ((uint)f2bf(hi) << 16);
}

// out[n][j] = relu(b[j] + sum_k in[n][k] * W[j][k])  (+ xres[n][j] if RESID)
// MFMA 16x16x32 bf16; one wave per 16-row tile (in-place safe for RESID:
// each tile's rows are read and written only by the owning wave).
// A and B use the same assumed k-bijection (dot invariant); C layout is the
// m89-verified col=lane&15, row=(lane>>4)*4+reg.
// launch_bounds(256,4): VGPR=104 fits 4 waves/EU; 32KB LDS fits 4 blocks/CU.
template<bool RESID, bool BF16OUT>
__global__ __launch_bounds__(256, 4)
void linear_mfma_kernel(const float* in, const float* __restrict__ W,
                        const float* __restrict__ b, const float* __restrict__ xres,
                        void* outv, int n_tiles)
{
    __shared__ uint4 Wl[128 * 16];   // 32 KB, 16B-chunk XOR swizzle

    const int t = threadIdx.x;
    for (int q = t; q < 2048; q += 256) {
        const int j = q >> 4, c = q & 15;
        const float4 lo = ((const float4*)(W + j * 128 + c * 8))[0];
        const float4 hi = ((const float4*)(W + j * 128 + c * 8))[1];
        uint4 pk;
        pk.x = pack2(lo.x, lo.y); pk.y = pack2(lo.z, lo.w);
        pk.z = pack2(hi.x, hi.y); pk.w = pack2(hi.z, hi.w);
        Wl[j * 16 + (c ^ (j & 15))] = pk;
    }
    __syncthreads();

    const int lane = t & 63;
    const int lo4 = lane & 15;
    const int g   = lane >> 4;

    float bias[8];
    #pragma unroll
    for (int ct = 0; ct < 8; ++ct) bias[ct] = b[ct * 16 + lo4];

    const int wid = (blockIdx.x * 256 + t) >> 6;
    const int nw  = (gridDim.x * 256) >> 6;

    for (int tile = wid; tile < n_tiles; tile += nw) {
        const int arow = tile * 16 + lo4;
        const float4* ap = (const float4*)(in + (size_t)arow * DIM + g * 32);
        float4 v[8];
        #pragma unroll
        for (int i = 0; i < 8; ++i) v[i] = ap[i];

        bf16x8 afrag[4];
        #pragma unroll
        for (int ks = 0; ks < 4; ++ks) {
            union { bf16x8 v8; uint u[4]; } a;
            a.u[0] = pack2(v[2*ks].x,   v[2*ks].y);
            a.u[1] = pack2(v[2*ks].z,   v[2*ks].w);
            a.u[2] = pack2(v[2*ks+1].x, v[2*ks+1].y);
            a.u[3] = pack2(v[2*ks+1].z, v[2*ks+1].w);
            afrag[ks] = a.v8;
        }

        f32x4 acc[8];
        #pragma unroll
        for (int ct = 0; ct < 8; ++ct)
            acc[ct] = (f32x4){bias[ct], bias[ct], bias[ct], bias[ct]};

        #pragma unroll
        for (int ks = 0; ks < 4; ++ks) {
            #pragma unroll
            for (int ct = 0; ct < 8; ++ct) {
                const int jrow = ct * 16 + lo4;
                const bf16x8 bfrag = *((const bf16x8*)&Wl[jrow * 16 + ((g * 4 + ks) ^ lo4)]);
                acc[ct] = __builtin_amdgcn_mfma_f32_16x16x32_bf16(afrag[ks], bfrag, acc[ct], 0, 0, 0);
            }
        }

        #pragma unroll
        for (int ct = 0; ct < 8; ++ct) {
            #pragma unroll
            for (int r = 0; r < 4; ++r) {
                const int orow = tile * 16 + g * 4 + r;
                const int ocol = ct * 16 + lo4;
                float val = fmaxf(acc[ct][r], 0.f);
                if constexpr (RESID) val += xres[(size_t)orow * DIM + ocol];
                if constexpr (BF16OUT)
                    ((ushort*)outv)[(size_t)orow * DIM + ocol] = f2bf(val);
                else
                    ((float*)outv)[(size_t)orow * DIM + ocol] = val;
            }
        }
    }
}

// Single-pass bucket scatter: per-block LDS hist -> one global atomicAdd per
// (block,bucket) reserves a contiguous run inside the bucket's fixed-capacity
// region bedges[b*BCAP ..] -> writes land in ~64B runs. gcur must be zeroed.
__global__ __launch_bounds__(256)
void bucket_scatter_kernel(const int* __restrict__ ei, int* __restrict__ gcur,
                           uint* __restrict__ bedges, int n_edges, int nb)
{
    __shared__ int histL[NBMAX];
    __shared__ int curL[NBMAX];
    const int t = threadIdx.x;
    for (int i = t; i < nb; i += 256) histL[i] = 0;
    __syncthreads();
    const int chunk = (n_edges + gridDim.x - 1) / gridDim.x;
    const int e0 = blockIdx.x * chunk;
    const int e1 = min(e0 + chunk, n_edges);
    for (int e = e0 + t; e < e1; e += 256)
        atomicAdd(&histL[ei[n_edges + e] >> 7], 1);
    __syncthreads();
    for (int i = t; i < nb; i += 256)
        curL[i] = histL[i] ? atomicAdd(&gcur[i], histL[i]) : 0;   // base within bucket
    __syncthreads();
    for (int e = e0 + t; e < e1; e += 256) {
        const int src = ei[e];
        const int dst = ei[n_edges + e];
        const int b = dst >> 7;
        const int pos = atomicAdd(&curL[b], 1);
        if (pos < BCAP)
            bedges[(size_t)b * BCAP + pos] = ((uint)src << 7) | (uint)(dst & 127);
    }
}

// Per-bucket gather: stage the bucket's packed edges in LDS (one global read),
// sort to exact-node order with int LDS atomics, then pull: one wave per node,
// broadcast src from LDS, coalesced 256B msg reads, register fp32 accumulate,
// one coalesced row write. Full coverage -> no agg memset needed.
__global__ __launch_bounds__(512)
void bucket_gather_kernel(const uint* __restrict__ msg, const int* __restrict__ gcur,
                          const uint* __restrict__ bedges, float* __restrict__ agg,
                          int n_nodes)
{
    __shared__ uint edgesL[BCAP];    // 16 KB
    __shared__ int  srcL[BCAP];      // 16 KB
    __shared__ int histL[BNODES];
    __shared__ int inclL[BNODES];
    __shared__ int cursL[BNODES];

    const int t = threadIdx.x;
    const int b = blockIdx.x;
    const int cnt = min(gcur[b], BCAP);
    const uint* be = bedges + (size_t)b * BCAP;

    if (t < BNODES) histL[t] = 0;
    __syncthreads();
    for (int i = t; i < cnt; i += 512) {
        const uint p = be[i];
        edgesL[i] = p;
        atomicAdd(&histL[p & 127u], 1);
    }
    __syncthreads();
    if (t < BNODES) inclL[t] = histL[t];
    for (int off = 1; off < BNODES; off <<= 1) {
        int add = 0;
        __syncthreads();
        if (t < BNODES && t >= off) add = inclL[t - off];
        __syncthreads();
        if (t < BNODES) inclL[t] += add;
    }
    __syncthreads();
    if (t < BNODES) cursL[t] = inclL[t] - histL[t];
    __syncthreads();
    for (int i = t; i < cnt; i += 512) {
        const uint p = edgesL[i];
        const int pos = atomicAdd(&cursL[p & 127u], 1);
        srcL[pos] = (int)(p >> 7);
    }
    __syncthreads();

    const int lane = t & 63;
    const int w = t >> 6;            // 8 waves
    for (int dl = w; dl < BNODES; dl += 8) {
        const int node = b * BNODES + dl;
        if (node >= n_nodes) break;          // wave-uniform
        const int e1 = inclL[dl];
        const int e0 = e1 - histL[dl];
        float a0 = 0.f, a1 = 0.f;
        int i = e0;
        for (; i + 4 <= e1; i += 4) {
            const int sA = srcL[i + 0], sB = srcL[i + 1];
            const int sC = srcL[i + 2], sD = srcL[i + 3];
            const uint mA = msg[(size_t)sA * 64 + lane];
            const uint mB = msg[(size_t)sB * 64 + lane];
            const uint mC = msg[(size_t)sC * 64 + lane];
            const uint mD = msg[(size_t)sD * 64 + lane];
            a0 += __uint_as_float(mA << 16) + __uint_as_float(mB << 16)
                + __uint_as_float(mC << 16) + __uint_as_float(mD << 16);
            a1 += __uint_as_float(mA & 0xffff0000u) + __uint_as_float(mB & 0xffff0000u)
                + __uint_as_float(mC & 0xffff0000u) + __uint_as_float(mD & 0xffff0000u);
        }
        for (; i < e1; ++i) {
            const uint m = msg[(size_t)srcL[i] * 64 + lane];
            a0 += __uint_as_float(m << 16);
            a1 += __uint_as_float(m & 0xffff0000u);
        }
        ((float2*)(agg + (size_t)node * DIM))[lane] = make_float2(a0, a1);
    }
}

extern "C" void kernel_launch(void* const* d_in, const int* in_sizes, int n_in,
                              void* d_out, int out_size, void* d_ws, size_t ws_size,
                              hipStream_t stream)
{
    const float* x  = (const float*)d_in[0];
    const int*   ei = (const int*)d_in[1];
    const float* Wm = (const float*)d_in[2];
    const float* bm = (const float*)d_in[3];
    const float* Wu = (const float*)d_in[4];
    const float* bu = (const float*)d_in[5];

    const int N = in_sizes[0] / DIM;   // 100000
    const int E = in_sizes[1] / 2;     // 1600000
    const int nb = (N + BNODES - 1) / BNODES;   // 782

    // workspace: msg 25.6MB | gcur ~4KB | bedges nb*BCAP*4 = 12.8MB  (~38.4MB)
    char* ws = (char*)d_ws;
    ushort* msg = (ushort*)ws;
    size_t o = (size_t)N * DIM * sizeof(ushort);
    int* gcur = (int*)(ws + o); o += (size_t)NBMAX * 4;
    o = (o + 255) & ~(size_t)255;
    uint* bedges = (uint*)(ws + o);

    float* out = (float*)d_out;
    float* agg = out;                  // agg lives in d_out; update runs in-place

    const int n_tiles = N / 16;

    // 1) messages (bf16) = relu(x @ Wm^T + bm) -> ws
    linear_mfma_kernel<false, true><<<1024, 256, 0, stream>>>(x, Wm, bm, nullptr, msg, n_tiles);

    // 2) single-pass bucket partition (128 nodes/bucket, fixed-capacity regions)
    hipMemsetAsync(gcur, 0, (size_t)nb * 4, stream);
    bucket_scatter_kernel<<<128, 256, 0, stream>>>(ei, gcur, bedges, E, nb);

    // 3) per-bucket LDS sort + pull gather -> d_out (full coverage, no memset)
    bucket_gather_kernel<<<nb, 512, 0, stream>>>((const uint*)msg, gcur, bedges, agg, N);

    // 4) out = relu(agg @ Wu^T + bu) + x   (in-place on d_out)
    linear_mfma_kernel<true, false><<<1024, 256, 0, stream>>>(agg, Wu, bu, x, out, n_tiles);
}

// Round 7
// 166.118 us; speedup vs baseline: 1.6072x; 1.6072x over previous
//
#include <hip/hip_runtime.h>
#include <hip/hip_bf16.h>

#define DIM 128
#define BNODES 128      // dst nodes per bucket (dst>>7 = bucket, dst&127 = local)
#define NBMAX 1024      // bucket capacity in LDS hist (nb = 782 for N=100000)
#define BCAP 4096       // max edges per bucket region (mean 2046, +45 sigma)

typedef __attribute__((ext_vector_type(8))) short bf16x8;
typedef __attribute__((ext_vector_type(4))) float f32x4;

__device__ inline ushort f2bf(float f) {
    uint u = __float_as_uint(f);
    u += 0x7fffu + ((u >> 16) & 1u);   // RNE
    return (ushort)(u >> 16);
}
__device__ inline uint pack2(float lo, float hi) {
    return (uint)f2bf(lo) | ((uint)f2bf(hi) << 16);
}

// out[n][j] = relu(b[j] + sum_k in[n][k] * W[j][k])  (+ xres[n][j] if RESID)
// MFMA 16x16x32 bf16; one wave per 16-row tile (in-place safe for RESID:
// each tile's rows are read and written only by the owning wave).
// A and B use the same assumed k-bijection (dot invariant); C layout is the
// m89-verified col=lane&15, row=(lane>>4)*4+reg.
// launch_bounds(256,2): kernel's live set is ~104 VGPR — forcing 4 waves/EU
// (round 6) spilled to scratch and DOUBLED the kernel time. At VGPR=104 the
// HW already allows 4 blocks/CU; grid=1024 fills them.
template<bool RESID, bool BF16OUT>
__global__ __launch_bounds__(256, 2)
void linear_mfma_kernel(const float* in, const float* __restrict__ W,
                        const float* __restrict__ b, const float* __restrict__ xres,
                        void* outv, int n_tiles)
{
    __shared__ uint4 Wl[128 * 16];   // 32 KB, 16B-chunk XOR swizzle

    const int t = threadIdx.x;
    for (int q = t; q < 2048; q += 256) {
        const int j = q >> 4, c = q & 15;
        const float4 lo = ((const float4*)(W + j * 128 + c * 8))[0];
        const float4 hi = ((const float4*)(W + j * 128 + c * 8))[1];
        uint4 pk;
        pk.x = pack2(lo.x, lo.y); pk.y = pack2(lo.z, lo.w);
        pk.z = pack2(hi.x, hi.y); pk.w = pack2(hi.z, hi.w);
        Wl[j * 16 + (c ^ (j & 15))] = pk;
    }
    __syncthreads();

    const int lane = t & 63;
    const int lo4 = lane & 15;
    const int g   = lane >> 4;

    float bias[8];
    #pragma unroll
    for (int ct = 0; ct < 8; ++ct) bias[ct] = b[ct * 16 + lo4];

    const int wid = (blockIdx.x * 256 + t) >> 6;
    const int nw  = (gridDim.x * 256) >> 6;

    for (int tile = wid; tile < n_tiles; tile += nw) {
        const int arow = tile * 16 + lo4;
        const float4* ap = (const float4*)(in + (size_t)arow * DIM + g * 32);
        float4 v[8];
        #pragma unroll
        for (int i = 0; i < 8; ++i) v[i] = ap[i];

        bf16x8 afrag[4];
        #pragma unroll
        for (int ks = 0; ks < 4; ++ks) {
            union { bf16x8 v8; uint u[4]; } a;
            a.u[0] = pack2(v[2*ks].x,   v[2*ks].y);
            a.u[1] = pack2(v[2*ks].z,   v[2*ks].w);
            a.u[2] = pack2(v[2*ks+1].x, v[2*ks+1].y);
            a.u[3] = pack2(v[2*ks+1].z, v[2*ks+1].w);
            afrag[ks] = a.v8;
        }

        f32x4 acc[8];
        #pragma unroll
        for (int ct = 0; ct < 8; ++ct)
            acc[ct] = (f32x4){bias[ct], bias[ct], bias[ct], bias[ct]};

        #pragma unroll
        for (int ks = 0; ks < 4; ++ks) {
            #pragma unroll
            for (int ct = 0; ct < 8; ++ct) {
                const int jrow = ct * 16 + lo4;
                const bf16x8 bfrag = *((const bf16x8*)&Wl[jrow * 16 + ((g * 4 + ks) ^ lo4)]);
                acc[ct] = __builtin_amdgcn_mfma_f32_16x16x32_bf16(afrag[ks], bfrag, acc[ct], 0, 0, 0);
            }
        }

        #pragma unroll
        for (int ct = 0; ct < 8; ++ct) {
            #pragma unroll
            for (int r = 0; r < 4; ++r) {
                const int orow = tile * 16 + g * 4 + r;
                const int ocol = ct * 16 + lo4;
                float val = fmaxf(acc[ct][r], 0.f);
                if constexpr (RESID) val += xres[(size_t)orow * DIM + ocol];
                if constexpr (BF16OUT)
                    ((ushort*)outv)[(size_t)orow * DIM + ocol] = f2bf(val);
                else
                    ((float*)outv)[(size_t)orow * DIM + ocol] = val;
            }
        }
    }
}

// Single-pass bucket scatter: per-block LDS hist -> one global atomicAdd per
// (block,bucket) reserves a contiguous run inside the bucket's fixed-capacity
// region bedges[b*BCAP ..] -> writes land in ~64B runs. gcur must be zeroed.
__global__ __launch_bounds__(256)
void bucket_scatter_kernel(const int* __restrict__ ei, int* __restrict__ gcur,
                           uint* __restrict__ bedges, int n_edges, int nb)
{
    __shared__ int histL[NBMAX];
    __shared__ int curL[NBMAX];
    const int t = threadIdx.x;
    for (int i = t; i < nb; i += 256) histL[i] = 0;
    __syncthreads();
    const int chunk = (n_edges + gridDim.x - 1) / gridDim.x;
    const int e0 = blockIdx.x * chunk;
    const int e1 = min(e0 + chunk, n_edges);
    for (int e = e0 + t; e < e1; e += 256)
        atomicAdd(&histL[ei[n_edges + e] >> 7], 1);
    __syncthreads();
    for (int i = t; i < nb; i += 256)
        curL[i] = histL[i] ? atomicAdd(&gcur[i], histL[i]) : 0;   // base within bucket
    __syncthreads();
    for (int e = e0 + t; e < e1; e += 256) {
        const int src = ei[e];
        const int dst = ei[n_edges + e];
        const int b = dst >> 7;
        const int pos = atomicAdd(&curL[b], 1);
        if (pos < BCAP)
            bedges[(size_t)b * BCAP + pos] = ((uint)src << 7) | (uint)(dst & 127);
    }
}

// Per-bucket gather: stage the bucket's packed edges in LDS (one global read),
// sort to exact-node order with int LDS atomics, then pull: one wave per node,
// broadcast src from LDS, coalesced 256B msg reads, register fp32 accumulate,
// one coalesced row write. Full coverage -> no agg memset needed.
__global__ __launch_bounds__(512)
void bucket_gather_kernel(const uint* __restrict__ msg, const int* __restrict__ gcur,
                          const uint* __restrict__ bedges, float* __restrict__ agg,
                          int n_nodes)
{
    __shared__ uint edgesL[BCAP];    // 16 KB
    __shared__ int  srcL[BCAP];      // 16 KB
    __shared__ int histL[BNODES];
    __shared__ int inclL[BNODES];
    __shared__ int cursL[BNODES];

    const int t = threadIdx.x;
    const int b = blockIdx.x;
    const int cnt = min(gcur[b], BCAP);
    const uint* be = bedges + (size_t)b * BCAP;

    if (t < BNODES) histL[t] = 0;
    __syncthreads();
    for (int i = t; i < cnt; i += 512) {
        const uint p = be[i];
        edgesL[i] = p;
        atomicAdd(&histL[p & 127u], 1);
    }
    __syncthreads();
    if (t < BNODES) inclL[t] = histL[t];
    for (int off = 1; off < BNODES; off <<= 1) {
        int add = 0;
        __syncthreads();
        if (t < BNODES && t >= off) add = inclL[t - off];
        __syncthreads();
        if (t < BNODES) inclL[t] += add;
    }
    __syncthreads();
    if (t < BNODES) cursL[t] = inclL[t] - histL[t];
    __syncthreads();
    for (int i = t; i < cnt; i += 512) {
        const uint p = edgesL[i];
        const int pos = atomicAdd(&cursL[p & 127u], 1);
        srcL[pos] = (int)(p >> 7);
    }
    __syncthreads();

    const int lane = t & 63;
    const int w = t >> 6;            // 8 waves
    for (int dl = w; dl < BNODES; dl += 8) {
        const int node = b * BNODES + dl;
        if (node >= n_nodes) break;          // wave-uniform
        const int e1 = inclL[dl];
        const int e0 = e1 - histL[dl];
        float a0 = 0.f, a1 = 0.f;
        int i = e0;
        for (; i + 4 <= e1; i += 4) {
            const int sA = srcL[i + 0], sB = srcL[i + 1];
            const int sC = srcL[i + 2], sD = srcL[i + 3];
            const uint mA = msg[(size_t)sA * 64 + lane];
            const uint mB = msg[(size_t)sB * 64 + lane];
            const uint mC = msg[(size_t)sC * 64 + lane];
            const uint mD = msg[(size_t)sD * 64 + lane];
            a0 += __uint_as_float(mA << 16) + __uint_as_float(mB << 16)
                + __uint_as_float(mC << 16) + __uint_as_float(mD << 16);
            a1 += __uint_as_float(mA & 0xffff0000u) + __uint_as_float(mB & 0xffff0000u)
                + __uint_as_float(mC & 0xffff0000u) + __uint_as_float(mD & 0xffff0000u);
        }
        for (; i < e1; ++i) {
            const uint m = msg[(size_t)srcL[i] * 64 + lane];
            a0 += __uint_as_float(m << 16);
            a1 += __uint_as_float(m & 0xffff0000u);
        }
        ((float2*)(agg + (size_t)node * DIM))[lane] = make_float2(a0, a1);
    }
}

extern "C" void kernel_launch(void* const* d_in, const int* in_sizes, int n_in,
                              void* d_out, int out_size, void* d_ws, size_t ws_size,
                              hipStream_t stream)
{
    const float* x  = (const float*)d_in[0];
    const int*   ei = (const int*)d_in[1];
    const float* Wm = (const float*)d_in[2];
    const float* bm = (const float*)d_in[3];
    const float* Wu = (const float*)d_in[4];
    const float* bu = (const float*)d_in[5];

    const int N = in_sizes[0] / DIM;   // 100000
    const int E = in_sizes[1] / 2;     // 1600000
    const int nb = (N + BNODES - 1) / BNODES;   // 782

    // workspace: msg 25.6MB | gcur ~4KB | bedges nb*BCAP*4 = 12.8MB  (~38.4MB)
    char* ws = (char*)d_ws;
    ushort* msg = (ushort*)ws;
    size_t o = (size_t)N * DIM * sizeof(ushort);
    int* gcur = (int*)(ws + o); o += (size_t)NBMAX * 4;
    o = (o + 255) & ~(size_t)255;
    uint* bedges = (uint*)(ws + o);

    float* out = (float*)d_out;
    float* agg = out;                  // agg lives in d_out; update runs in-place

    const int n_tiles = N / 16;

    // 1) messages (bf16) = relu(x @ Wm^T + bm) -> ws
    linear_mfma_kernel<false, true><<<1024, 256, 0, stream>>>(x, Wm, bm, nullptr, msg, n_tiles);

    // 2) single-pass bucket partition (128 nodes/bucket, fixed-capacity regions)
    hipMemsetAsync(gcur, 0, (size_t)nb * 4, stream);
    bucket_scatter_kernel<<<128, 256, 0, stream>>>(ei, gcur, bedges, E, nb);

    // 3) per-bucket LDS sort + pull gather -> d_out (full coverage, no memset)
    bucket_gather_kernel<<<nb, 512, 0, stream>>>((const uint*)msg, gcur, bedges, agg, N);

    // 4) out = relu(agg @ Wu^T + bu) + x   (in-place on d_out)
    linear_mfma_kernel<true, false><<<1024, 256, 0, stream>>>(agg, Wu, bu, x, out, n_tiles);
}

// Round 8
// 165.454 us; speedup vs baseline: 1.6137x; 1.0040x over previous
//
#include <hip/hip_runtime.h>
#include <hip/hip_bf16.h>

#define DIM 128
#define BNODES 128      // dst nodes per bucket (dst>>7 = bucket, dst&127 = local)
#define NBMAX 1024      // bucket capacity in LDS hist (nb = 782 for N=100000)
#define BCAP 4096       // max edges per bucket region (mean 2046, +45 sigma)

typedef __attribute__((ext_vector_type(8))) short bf16x8;
typedef __attribute__((ext_vector_type(4))) float f32x4;

__device__ inline ushort f2bf(float f) {
    uint u = __float_as_uint(f);
    u += 0x7fffu + ((u >> 16) & 1u);   // RNE
    return (ushort)(u >> 16);
}
__device__ inline uint pack2(float lo, float hi) {
    return (uint)f2bf(lo) | ((uint)f2bf(hi) << 16);
}

// out[n][j] = relu(b[j] + sum_k in[n][k] * W[j][k])  (+ xres[n][j] if RESID)
// MFMA 16x16x32 bf16; one wave per 16-row tile (in-place safe for RESID:
// each tile's rows are read and written only by the owning wave).
// A and B use the same assumed k-bijection (dot invariant); C layout is the
// m89-verified col=lane&15, row=(lane>>4)*4+reg.
// launch_bounds(256,2): kernel's live set is ~104 VGPR — forcing 4 waves/EU
// (round 6) spilled to scratch and DOUBLED the kernel time. At VGPR=104 the
// HW already allows 4 blocks/CU; grid=1024 fills them.
template<bool RESID, bool BF16OUT>
__global__ __launch_bounds__(256, 2)
void linear_mfma_kernel(const float* in, const float* __restrict__ W,
                        const float* __restrict__ b, const float* __restrict__ xres,
                        void* outv, int n_tiles)
{
    __shared__ uint4 Wl[128 * 16];   // 32 KB, 16B-chunk XOR swizzle

    const int t = threadIdx.x;
    for (int q = t; q < 2048; q += 256) {
        const int j = q >> 4, c = q & 15;
        const float4 lo = ((const float4*)(W + j * 128 + c * 8))[0];
        const float4 hi = ((const float4*)(W + j * 128 + c * 8))[1];
        uint4 pk;
        pk.x = pack2(lo.x, lo.y); pk.y = pack2(lo.z, lo.w);
        pk.z = pack2(hi.x, hi.y); pk.w = pack2(hi.z, hi.w);
        Wl[j * 16 + (c ^ (j & 15))] = pk;
    }
    __syncthreads();

    const int lane = t & 63;
    const int lo4 = lane & 15;
    const int g   = lane >> 4;

    float bias[8];
    #pragma unroll
    for (int ct = 0; ct < 8; ++ct) bias[ct] = b[ct * 16 + lo4];

    const int wid = (blockIdx.x * 256 + t) >> 6;
    const int nw  = (gridDim.x * 256) >> 6;

    for (int tile = wid; tile < n_tiles; tile += nw) {
        const int arow = tile * 16 + lo4;
        const float4* ap = (const float4*)(in + (size_t)arow * DIM + g * 32);
        float4 v[8];
        #pragma unroll
        for (int i = 0; i < 8; ++i) v[i] = ap[i];

        bf16x8 afrag[4];
        #pragma unroll
        for (int ks = 0; ks < 4; ++ks) {
            union { bf16x8 v8; uint u[4]; } a;
            a.u[0] = pack2(v[2*ks].x,   v[2*ks].y);
            a.u[1] = pack2(v[2*ks].z,   v[2*ks].w);
            a.u[2] = pack2(v[2*ks+1].x, v[2*ks+1].y);
            a.u[3] = pack2(v[2*ks+1].z, v[2*ks+1].w);
            afrag[ks] = a.v8;
        }

        f32x4 acc[8];
        #pragma unroll
        for (int ct = 0; ct < 8; ++ct)
            acc[ct] = (f32x4){bias[ct], bias[ct], bias[ct], bias[ct]};

        #pragma unroll
        for (int ks = 0; ks < 4; ++ks) {
            #pragma unroll
            for (int ct = 0; ct < 8; ++ct) {
                const int jrow = ct * 16 + lo4;
                const bf16x8 bfrag = *((const bf16x8*)&Wl[jrow * 16 + ((g * 4 + ks) ^ lo4)]);
                acc[ct] = __builtin_amdgcn_mfma_f32_16x16x32_bf16(afrag[ks], bfrag, acc[ct], 0, 0, 0);
            }
        }

        #pragma unroll
        for (int ct = 0; ct < 8; ++ct) {
            #pragma unroll
            for (int r = 0; r < 4; ++r) {
                const int orow = tile * 16 + g * 4 + r;
                const int ocol = ct * 16 + lo4;
                float val = fmaxf(acc[ct][r], 0.f);
                if constexpr (RESID) val += xres[(size_t)orow * DIM + ocol];
                if constexpr (BF16OUT)
                    ((ushort*)outv)[(size_t)orow * DIM + ocol] = f2bf(val);
                else
                    ((float*)outv)[(size_t)orow * DIM + ocol] = val;
            }
        }
    }
}

// Single-pass bucket scatter: per-block LDS hist -> one global atomicAdd per
// (block,bucket) reserves a contiguous run inside the bucket's fixed-capacity
// region bedges[b*BCAP ..] -> writes land in ~64B runs. gcur must be zeroed.
// grid=1024 (round 7 had 128 -> 2 waves/CU -> pure latency exposure, 71 us).
__global__ __launch_bounds__(256)
void bucket_scatter_kernel(const int* __restrict__ ei, int* __restrict__ gcur,
                           uint* __restrict__ bedges, int n_edges, int nb)
{
    __shared__ int histL[NBMAX];
    __shared__ int curL[NBMAX];
    const int t = threadIdx.x;
    for (int i = t; i < nb; i += 256) histL[i] = 0;
    __syncthreads();
    const int chunk = (n_edges + gridDim.x - 1) / gridDim.x;
    const int e0 = blockIdx.x * chunk;
    const int e1 = min(e0 + chunk, n_edges);
    for (int e = e0 + t; e < e1; e += 256)
        atomicAdd(&histL[ei[n_edges + e] >> 7], 1);
    __syncthreads();
    for (int i = t; i < nb; i += 256)
        curL[i] = histL[i] ? atomicAdd(&gcur[i], histL[i]) : 0;   // base within bucket
    __syncthreads();
    for (int e = e0 + t; e < e1; e += 256) {
        const int src = ei[e];
        const int dst = ei[n_edges + e];
        const int b = dst >> 7;
        const int pos = atomicAdd(&curL[b], 1);
        if (pos < BCAP)
            bedges[(size_t)b * BCAP + pos] = ((uint)src << 7) | (uint)(dst & 127);
    }
}

// Per-bucket gather: stage the bucket's packed edges in LDS (one global read),
// sort to exact-node order with int LDS atomics, then pull: one wave per node,
// broadcast src from LDS, coalesced 256B msg reads, register fp32 accumulate,
// one coalesced row write. Full coverage -> no agg memset needed.
__global__ __launch_bounds__(512)
void bucket_gather_kernel(const uint* __restrict__ msg, const int* __restrict__ gcur,
                          const uint* __restrict__ bedges, float* __restrict__ agg,
                          int n_nodes)
{
    __shared__ uint edgesL[BCAP];    // 16 KB
    __shared__ int  srcL[BCAP];      // 16 KB
    __shared__ int histL[BNODES];
    __shared__ int inclL[BNODES];
    __shared__ int cursL[BNODES];

    const int t = threadIdx.x;
    const int b = blockIdx.x;
    const int cnt = min(gcur[b], BCAP);
    const uint* be = bedges + (size_t)b * BCAP;

    if (t < BNODES) histL[t] = 0;
    __syncthreads();
    for (int i = t; i < cnt; i += 512) {
        const uint p = be[i];
        edgesL[i] = p;
        atomicAdd(&histL[p & 127u], 1);
    }
    __syncthreads();
    if (t < BNODES) inclL[t] = histL[t];
    for (int off = 1; off < BNODES; off <<= 1) {
        int add = 0;
        __syncthreads();
        if (t < BNODES && t >= off) add = inclL[t - off];
        __syncthreads();
        if (t < BNODES) inclL[t] += add;
    }
    __syncthreads();
    if (t < BNODES) cursL[t] = inclL[t] - histL[t];
    __syncthreads();
    for (int i = t; i < cnt; i += 512) {
        const uint p = edgesL[i];
        const int pos = atomicAdd(&cursL[p & 127u], 1);
        srcL[pos] = (int)(p >> 7);
    }
    __syncthreads();

    const int lane = t & 63;
    const int w = t >> 6;            // 8 waves
    for (int dl = w; dl < BNODES; dl += 8) {
        const int node = b * BNODES + dl;
        if (node >= n_nodes) break;          // wave-uniform
        const int e1 = inclL[dl];
        const int e0 = e1 - histL[dl];
        float a0 = 0.f, a1 = 0.f;
        int i = e0;
        for (; i + 4 <= e1; i += 4) {
            const int sA = srcL[i + 0], sB = srcL[i + 1];
            const int sC = srcL[i + 2], sD = srcL[i + 3];
            const uint mA = msg[(size_t)sA * 64 + lane];
            const uint mB = msg[(size_t)sB * 64 + lane];
            const uint mC = msg[(size_t)sC * 64 + lane];
            const uint mD = msg[(size_t)sD * 64 + lane];
            a0 += __uint_as_float(mA << 16) + __uint_as_float(mB << 16)
                + __uint_as_float(mC << 16) + __uint_as_float(mD << 16);
            a1 += __uint_as_float(mA & 0xffff0000u) + __uint_as_float(mB & 0xffff0000u)
                + __uint_as_float(mC & 0xffff0000u) + __uint_as_float(mD & 0xffff0000u);
        }
        for (; i < e1; ++i) {
            const uint m = msg[(size_t)srcL[i] * 64 + lane];
            a0 += __uint_as_float(m << 16);
            a1 += __uint_as_float(m & 0xffff0000u);
        }
        ((float2*)(agg + (size_t)node * DIM))[lane] = make_float2(a0, a1);
    }
}

extern "C" void kernel_launch(void* const* d_in, const int* in_sizes, int n_in,
                              void* d_out, int out_size, void* d_ws, size_t ws_size,
                              hipStream_t stream)
{
    const float* x  = (const float*)d_in[0];
    const int*   ei = (const int*)d_in[1];
    const float* Wm = (const float*)d_in[2];
    const float* bm = (const float*)d_in[3];
    const float* Wu = (const float*)d_in[4];
    const float* bu = (const float*)d_in[5];

    const int N = in_sizes[0] / DIM;   // 100000
    const int E = in_sizes[1] / 2;     // 1600000
    const int nb = (N + BNODES - 1) / BNODES;   // 782

    // workspace: msg 25.6MB | gcur ~4KB | bedges nb*BCAP*4 = 12.8MB  (~38.4MB)
    char* ws = (char*)d_ws;
    ushort* msg = (ushort*)ws;
    size_t o = (size_t)N * DIM * sizeof(ushort);
    int* gcur = (int*)(ws + o); o += (size_t)NBMAX * 4;
    o = (o + 255) & ~(size_t)255;
    uint* bedges = (uint*)(ws + o);

    float* out = (float*)d_out;
    float* agg = out;                  // agg lives in d_out; update runs in-place

    const int n_tiles = N / 16;

    // 1) messages (bf16) = relu(x @ Wm^T + bm) -> ws
    linear_mfma_kernel<false, true><<<1024, 256, 0, stream>>>(x, Wm, bm, nullptr, msg, n_tiles);

    // 2) single-pass bucket partition (128 nodes/bucket, fixed-capacity regions)
    hipMemsetAsync(gcur, 0, (size_t)nb * 4, stream);
    bucket_scatter_kernel<<<1024, 256, 0, stream>>>(ei, gcur, bedges, E, nb);

    // 3) per-bucket LDS sort + pull gather -> d_out (full coverage, no memset)
    bucket_gather_kernel<<<nb, 512, 0, stream>>>((const uint*)msg, gcur, bedges, agg, N);

    // 4) out = relu(agg @ Wu^T + bu) + x   (in-place on d_out)
    linear_mfma_kernel<true, false><<<1024, 256, 0, stream>>>(agg, Wu, bu, x, out, n_tiles);
}

// Round 9
// 157.649 us; speedup vs baseline: 1.6936x; 1.0495x over previous
//
#include <hip/hip_runtime.h>
#include <hip/hip_bf16.h>

#define DIM 128
#define BNODES 128      // fine bucket = 128 dst nodes (dst>>7)
#define CNODES 1024     // coarse bucket = 1024 dst nodes (dst>>10)
#define NCMAX 128       // coarse-bucket capacity in LDS (ncb = 98 for N=100000)
#define NBMAX 1024      // fine-bucket cursor array size (nb = 782)
#define CCAP 20480      // edges per coarse region (mean 16384, +32 sigma)
#define BCAP 4096       // edges per fine region (mean 2046, +45 sigma)
#define SPLITB 8        // blocks per coarse bucket in pass B

typedef __attribute__((ext_vector_type(8))) short bf16x8;
typedef __attribute__((ext_vector_type(4))) float f32x4;

__device__ inline ushort f2bf(float f) {
    uint u = __float_as_uint(f);
    u += 0x7fffu + ((u >> 16) & 1u);   // RNE
    return (ushort)(u >> 16);
}
__device__ inline uint pack2(float lo, float hi) {
    return (uint)f2bf(lo) | ((uint)f2bf(hi) << 16);
}

// out[n][j] = relu(b[j] + sum_k in[n][k] * W[j][k])  (+ xres[n][j] if RESID)
// MFMA 16x16x32 bf16; one wave per 16-row tile (in-place safe for RESID).
// A and B use the same assumed k-bijection (dot invariant); C layout is the
// m89-verified col=lane&15, row=(lane>>4)*4+reg.
// (256,2): live set ~104 VGPR — round 6 proved forcing 4 waves/EU spills.
template<bool RESID, bool BF16OUT>
__global__ __launch_bounds__(256, 2)
void linear_mfma_kernel(const float* in, const float* __restrict__ W,
                        const float* __restrict__ b, const float* __restrict__ xres,
                        void* outv, int n_tiles)
{
    __shared__ uint4 Wl[128 * 16];   // 32 KB, 16B-chunk XOR swizzle

    const int t = threadIdx.x;
    for (int q = t; q < 2048; q += 256) {
        const int j = q >> 4, c = q & 15;
        const float4 lo = ((const float4*)(W + j * 128 + c * 8))[0];
        const float4 hi = ((const float4*)(W + j * 128 + c * 8))[1];
        uint4 pk;
        pk.x = pack2(lo.x, lo.y); pk.y = pack2(lo.z, lo.w);
        pk.z = pack2(hi.x, hi.y); pk.w = pack2(hi.z, hi.w);
        Wl[j * 16 + (c ^ (j & 15))] = pk;
    }
    __syncthreads();

    const int lane = t & 63;
    const int lo4 = lane & 15;
    const int g   = lane >> 4;

    float bias[8];
    #pragma unroll
    for (int ct = 0; ct < 8; ++ct) bias[ct] = b[ct * 16 + lo4];

    const int wid = (blockIdx.x * 256 + t) >> 6;
    const int nw  = (gridDim.x * 256) >> 6;

    for (int tile = wid; tile < n_tiles; tile += nw) {
        const int arow = tile * 16 + lo4;
        const float4* ap = (const float4*)(in + (size_t)arow * DIM + g * 32);
        float4 v[8];
        #pragma unroll
        for (int i = 0; i < 8; ++i) v[i] = ap[i];

        bf16x8 afrag[4];
        #pragma unroll
        for (int ks = 0; ks < 4; ++ks) {
            union { bf16x8 v8; uint u[4]; } a;
            a.u[0] = pack2(v[2*ks].x,   v[2*ks].y);
            a.u[1] = pack2(v[2*ks].z,   v[2*ks].w);
            a.u[2] = pack2(v[2*ks+1].x, v[2*ks+1].y);
            a.u[3] = pack2(v[2*ks+1].z, v[2*ks+1].w);
            afrag[ks] = a.v8;
        }

        f32x4 acc[8];
        #pragma unroll
        for (int ct = 0; ct < 8; ++ct)
            acc[ct] = (f32x4){bias[ct], bias[ct], bias[ct], bias[ct]};

        #pragma unroll
        for (int ks = 0; ks < 4; ++ks) {
            #pragma unroll
            for (int ct = 0; ct < 8; ++ct) {
                const int jrow = ct * 16 + lo4;
                const bf16x8 bfrag = *((const bf16x8*)&Wl[jrow * 16 + ((g * 4 + ks) ^ lo4)]);
                acc[ct] = __builtin_amdgcn_mfma_f32_16x16x32_bf16(afrag[ks], bfrag, acc[ct], 0, 0, 0);
            }
        }

        #pragma unroll
        for (int ct = 0; ct < 8; ++ct) {
            #pragma unroll
            for (int r = 0; r < 4; ++r) {
                const int orow = tile * 16 + g * 4 + r;
                const int ocol = ct * 16 + lo4;
                float val = fmaxf(acc[ct][r], 0.f);
                if constexpr (RESID) val += xres[(size_t)orow * DIM + ocol];
                if constexpr (BF16OUT)
                    ((ushort*)outv)[(size_t)orow * DIM + ocol] = f2bf(val);
                else
                    ((float*)outv)[(size_t)orow * DIM + ocol] = val;
            }
        }
    }
}

// Pass A: coarse partition by dst>>10 (98 targets). grid=1024 -> chunk 1563,
// run length = chunk/98 ~ 16 edges = 64B writes AND 16 waves/CU.
// Pack: src<<10 | (dst & 1023).
__global__ __launch_bounds__(256)
void coarse_scatter_kernel(const int* __restrict__ ei, int* __restrict__ ccur,
                           uint* __restrict__ cedges, int n_edges, int ncb)
{
    __shared__ int histL[NCMAX];
    __shared__ int curL[NCMAX];
    const int t = threadIdx.x;
    if (t < ncb) histL[t] = 0;
    __syncthreads();
    const int chunk = (n_edges + gridDim.x - 1) / gridDim.x;
    const int e0 = blockIdx.x * chunk;
    const int e1 = min(e0 + chunk, n_edges);
    for (int e = e0 + t; e < e1; e += 256)
        atomicAdd(&histL[ei[n_edges + e] >> 10], 1);
    __syncthreads();
    if (t < ncb)
        curL[t] = histL[t] ? atomicAdd(&ccur[t], histL[t]) : 0;
    __syncthreads();
    for (int e = e0 + t; e < e1; e += 256) {
        const int src = ei[e];
        const int dst = ei[n_edges + e];
        const int c = dst >> 10;
        const int pos = atomicAdd(&curL[c], 1);
        if (pos < CCAP)
            cedges[(size_t)c * CCAP + pos] = ((uint)src << 10) | (uint)(dst & 1023);
    }
}

// Pass B: refine each coarse region into its 8 fine buckets (dst>>7 = c*8+f).
// Contiguous reads; run length ~ 256 edges = 1KB writes. grid = ncb*SPLITB.
// Output pack: src<<7 | (dst & 127)  (what bucket_gather consumes).
__global__ __launch_bounds__(256)
void fine_scatter_kernel(const int* __restrict__ ccnt, const uint* __restrict__ cedges,
                         int* __restrict__ gcur, uint* __restrict__ bedges, int ncb)
{
    __shared__ int histL[SPLITB];
    __shared__ int curL[SPLITB];
    const int t = threadIdx.x;
    const int c = blockIdx.x / SPLITB;
    const int s = blockIdx.x % SPLITB;
    const int cnt = min(ccnt[c], CCAP);
    const int chunk = (cnt + SPLITB - 1) / SPLITB;
    const int e0 = s * chunk;
    const int e1 = min(e0 + chunk, cnt);
    if (t < SPLITB) histL[t] = 0;
    __syncthreads();
    const uint* ce = cedges + (size_t)c * CCAP;
    for (int i = e0 + t; i < e1; i += 256)
        atomicAdd(&histL[(ce[i] & 1023u) >> 7], 1);
    __syncthreads();
    if (t < SPLITB)
        curL[t] = histL[t] ? atomicAdd(&gcur[c * SPLITB + t], histL[t]) : 0;
    __syncthreads();
    for (int i = e0 + t; i < e1; i += 256) {
        const uint p = ce[i];
        const uint dl = p & 1023u;
        const int f = (int)(dl >> 7);
        const int pos = atomicAdd(&curL[f], 1);
        if (pos < BCAP)
            bedges[(size_t)(c * SPLITB + f) * BCAP + pos] = ((p >> 10) << 7) | (dl & 127u);
    }
}

// Per-bucket gather: stage packed edges in LDS, sort to exact-node order with
// int LDS atomics, then pull: one wave per node, broadcast src from LDS,
// coalesced 256B msg reads, register fp32 accumulate, one coalesced row write.
__global__ __launch_bounds__(512)
void bucket_gather_kernel(const uint* __restrict__ msg, const int* __restrict__ gcur,
                          const uint* __restrict__ bedges, float* __restrict__ agg,
                          int n_nodes)
{
    __shared__ uint edgesL[BCAP];    // 16 KB
    __shared__ int  srcL[BCAP];      // 16 KB
    __shared__ int histL[BNODES];
    __shared__ int inclL[BNODES];
    __shared__ int cursL[BNODES];

    const int t = threadIdx.x;
    const int b = blockIdx.x;
    const int cnt = min(gcur[b], BCAP);
    const uint* be = bedges + (size_t)b * BCAP;

    if (t < BNODES) histL[t] = 0;
    __syncthreads();
    for (int i = t; i < cnt; i += 512) {
        const uint p = be[i];
        edgesL[i] = p;
        atomicAdd(&histL[p & 127u], 1);
    }
    __syncthreads();
    if (t < BNODES) inclL[t] = histL[t];
    for (int off = 1; off < BNODES; off <<= 1) {
        int add = 0;
        __syncthreads();
        if (t < BNODES && t >= off) add = inclL[t - off];
        __syncthreads();
        if (t < BNODES) inclL[t] += add;
    }
    __syncthreads();
    if (t < BNODES) cursL[t] = inclL[t] - histL[t];
    __syncthreads();
    for (int i = t; i < cnt; i += 512) {
        const uint p = edgesL[i];
        const int pos = atomicAdd(&cursL[p & 127u], 1);
        srcL[pos] = (int)(p >> 7);
    }
    __syncthreads();

    const int lane = t & 63;
    const int w = t >> 6;            // 8 waves
    for (int dl = w; dl < BNODES; dl += 8) {
        const int node = b * BNODES + dl;
        if (node >= n_nodes) break;          // wave-uniform
        const int e1 = inclL[dl];
        const int e0 = e1 - histL[dl];
        float a0 = 0.f, a1 = 0.f;
        int i = e0;
        for (; i + 4 <= e1; i += 4) {
            const int sA = srcL[i + 0], sB = srcL[i + 1];
            const int sC = srcL[i + 2], sD = srcL[i + 3];
            const uint mA = msg[(size_t)sA * 64 + lane];
            const uint mB = msg[(size_t)sB * 64 + lane];
            const uint mC = msg[(size_t)sC * 64 + lane];
            const uint mD = msg[(size_t)sD * 64 + lane];
            a0 += __uint_as_float(mA << 16) + __uint_as_float(mB << 16)
                + __uint_as_float(mC << 16) + __uint_as_float(mD << 16);
            a1 += __uint_as_float(mA & 0xffff0000u) + __uint_as_float(mB & 0xffff0000u)
                + __uint_as_float(mC & 0xffff0000u) + __uint_as_float(mD & 0xffff0000u);
        }
        for (; i < e1; ++i) {
            const uint m = msg[(size_t)srcL[i] * 64 + lane];
            a0 += __uint_as_float(m << 16);
            a1 += __uint_as_float(m & 0xffff0000u);
        }
        ((float2*)(agg + (size_t)node * DIM))[lane] = make_float2(a0, a1);
    }
}

extern "C" void kernel_launch(void* const* d_in, const int* in_sizes, int n_in,
                              void* d_out, int out_size, void* d_ws, size_t ws_size,
                              hipStream_t stream)
{
    const float* x  = (const float*)d_in[0];
    const int*   ei = (const int*)d_in[1];
    const float* Wm = (const float*)d_in[2];
    const float* bm = (const float*)d_in[3];
    const float* Wu = (const float*)d_in[4];
    const float* bu = (const float*)d_in[5];

    const int N = in_sizes[0] / DIM;   // 100000
    const int E = in_sizes[1] / 2;     // 1600000
    const int nb  = (N + BNODES - 1) / BNODES;   // 782
    const int ncb = (N + CNODES - 1) / CNODES;   // 98

    // ws: msg 25.6MB | ccur+gcur ~4.5KB | cedges 98*20480*4 = 8.0MB |
    //     bedges 784*4096*4 = 12.9MB  -> ~46.5MB (< 51.2MB proven)
    char* ws = (char*)d_ws;
    ushort* msg = (ushort*)ws;
    size_t o = (size_t)N * DIM * sizeof(ushort);
    int* ccur = (int*)(ws + o); o += (size_t)NCMAX * 4;
    int* gcur = (int*)(ws + o); o += (size_t)NBMAX * 4;
    o = (o + 255) & ~(size_t)255;
    uint* cedges = (uint*)(ws + o); o += (size_t)ncb * CCAP * 4;
    o = (o + 255) & ~(size_t)255;
    uint* bedges = (uint*)(ws + o);

    float* out = (float*)d_out;
    float* agg = out;                  // agg lives in d_out; update runs in-place

    const int n_tiles = N / 16;

    // 1) messages (bf16) = relu(x @ Wm^T + bm) -> ws
    linear_mfma_kernel<false, true><<<1024, 256, 0, stream>>>(x, Wm, bm, nullptr, msg, n_tiles);

    // 2) two-pass radix partition by dst
    hipMemsetAsync(ccur, 0, (size_t)(NCMAX + NBMAX) * 4, stream);
    coarse_scatter_kernel<<<1024, 256, 0, stream>>>(ei, ccur, cedges, E, ncb);
    fine_scatter_kernel<<<ncb * SPLITB, 256, 0, stream>>>(ccur, cedges, gcur, bedges, ncb);

    // 3) per-bucket LDS sort + pull gather -> d_out (full coverage, no memset)
    bucket_gather_kernel<<<nb, 512, 0, stream>>>((const uint*)msg, gcur, bedges, agg, N);

    // 4) out = relu(agg @ Wu^T + bu) + x   (in-place on d_out)
    linear_mfma_kernel<true, false><<<1024, 256, 0, stream>>>(agg, Wu, bu, x, out, n_tiles);
}